// Round 6
// baseline (346.681 us; speedup 1.0000x reference)
//
#include <hip/hip_runtime.h>
#include <math.h>

// Problem constants
constexpr int cH  = 768;
constexpr int cDM = 1536;
constexpr int cN  = 16;
constexpr int cR  = 48;
constexpr int cB  = 2;
constexpr int cL  = 1024;
constexpr int cPS = 160;  // stacked ssm row: [fwd 80 | bwd 80]
constexpr int cCK = 4;    // scan chunks (chunk length = cL/cCK = 256)

typedef unsigned short u16;
typedef __attribute__((ext_vector_type(8))) short bf16x8;
typedef __attribute__((ext_vector_type(4))) float f32x4;

__device__ __forceinline__ u16 f2bf(float f) {
    unsigned u = __float_as_uint(f);
    u += 0x7FFF + ((u >> 16) & 1);          // RNE
    return (u16)(u >> 16);
}
__device__ __forceinline__ float bf2f(u16 h) {
    return __uint_as_float((unsigned)h << 16);
}

// ---------------------------------------------------------------------------
// fp32 -> bf16 convert (grid-stride)
// ---------------------------------------------------------------------------
__global__ __launch_bounds__(256)
void f2b_kernel(const float* __restrict__ in, u16* __restrict__ out, long n) {
    for (long i = (long)blockIdx.x * 256 + threadIdx.x; i < n; i += (long)gridDim.x * 256)
        out[i] = f2bf(in[i]);
}

// (rows x 48) fp32 -> (rows x 64) bf16, zero-padded
__global__ __launch_bounds__(256)
void padw_kernel(const float* __restrict__ in, u16* __restrict__ out, int rows) {
    int i = blockIdx.x * 256 + threadIdx.x;
    if (i >= rows * 64) return;
    int r = i >> 6, k = i & 63;
    out[i] = (k < cR) ? f2bf(in[r * cR + k]) : (u16)0;
}

// ssms (B,L,160) ts-slices -> (2,B,L,64) bf16 zero-padded
__global__ __launch_bounds__(256)
void tspad_kernel(const float* __restrict__ ssms, u16* __restrict__ out) {
    int i = blockIdx.x * 256 + threadIdx.x;    // exactly 2*B*L*64 = 262144
    int dirsel = i >> 17;
    int rem = i & 131071;
    int bl = rem >> 6, k = rem & 63;
    out[i] = (k < cR) ? f2bf(ssms[(long)bl * cPS + dirsel * 80 + k]) : (u16)0;
}

// yf (bf16) += yb (bf16), in place, 8 elems/thread
__global__ __launch_bounds__(256)
void comb_kernel(u16* __restrict__ yf, const u16* __restrict__ yb, long n8) {
    long i = (long)blockIdx.x * 256 + threadIdx.x;
    if (i >= n8) return;
    uint4 av = ((uint4*)yf)[i];
    uint4 bv = ((const uint4*)yb)[i];
    unsigned* ap = (unsigned*)&av;
    unsigned* bp = (unsigned*)&bv;
    #pragma unroll
    for (int j = 0; j < 4; ++j) {
        const float lo = bf2f((u16)(ap[j] & 0xffff)) + bf2f((u16)(bp[j] & 0xffff));
        const float hi = bf2f((u16)(ap[j] >> 16))    + bf2f((u16)(bp[j] >> 16));
        ap[j] = (unsigned)f2bf(lo) | ((unsigned)f2bf(hi) << 16);
    }
    ((uint4*)yf)[i] = av;
}

// ---------------------------------------------------------------------------
// bf16 MFMA NT GEMM (unchanged from round 4/5; see comments there).
// ---------------------------------------------------------------------------
__device__ __forceinline__ void gld_lds16(const u16* g, u16* l) {
    __builtin_amdgcn_global_load_lds(
        (const __attribute__((address_space(1))) unsigned int*)g,
        (__attribute__((address_space(3))) unsigned int*)l, 16, 0, 0);
}

template<int EPI>
__global__ __launch_bounds__(256, 3)
void gemm_mfma(const u16* __restrict__ A, const u16* __restrict__ B,
               const u16* __restrict__ B_hi,
               float* __restrict__ C0, float* __restrict__ C1,
               const float* __restrict__ bias, const float* __restrict__ bias_hi,
               int N2, int Kd, int lda, int ldb, int ldc,
               long sA, long sB, long sC, int splitRow, int kspl)
{
    __shared__ __align__(16) u16 shA[4096];   // [128][32] bf16, chunk-swizzled
    __shared__ __align__(16) u16 shB[4096];
    const int tid  = threadIdx.x;
    const int wid  = tid >> 6, lane = tid & 63;
    const int lr   = lane & 15, lc = lane >> 4;
    const int z    = blockIdx.z;
    const int bz   = z / kspl, ks = z % kspl;
    const int kpc  = Kd / kspl;
    const int kbeg = ks * kpc, kend = kbeg + kpc;
    const int n0 = blockIdx.x * 128, m0 = blockIdx.y * 128;

    const u16* Bsel = (B_hi != nullptr && m0 >= splitRow) ? B_hi : B;
    const float* biasp = (bias_hi != nullptr && m0 >= splitRow) ? bias_hi : bias;
    const int mro = (bias_hi != nullptr && m0 >= splitRow) ? splitRow : 0;

    const u16* Ab = A + (long)bz * sA;
    const u16* Bb = Bsel + (long)bz * sB;
    const int wm = (wid >> 1) * 64, wn = (wid & 1) * 64;

    f32x4 acc[4][4] = {};

    for (int k0 = kbeg; k0 < kend; k0 += 32) {
        __syncthreads();
        #pragma unroll
        for (int h = 0; h < 2; ++h) {
            const int q  = wid * 2 + h;            // 1KB stage unit
            const int rr = q * 16 + (lane >> 2);   // tile row this lane fills
            const int sw = (rr & 3) ^ ((rr >> 2) & 3);
            const int kg = k0 + (((lane & 3) ^ sw) << 3);  // inverse-swizzled src
            gld_lds16(Ab + (long)(m0 + rr) * lda + kg, &shA[q * 512]);
            int nr = n0 + rr; if (nr > N2 - 1) nr = N2 - 1;   // clamp partial N
            gld_lds16(Bb + (long)nr * ldb + kg, &shB[q * 512]);
        }
        __syncthreads();
        bf16x8 af[4], bfr[4];
        #pragma unroll
        for (int i = 0; i < 4; ++i) {
            const int ra  = wm + i * 16 + lr;
            const int swa = (ra & 3) ^ ((ra >> 2) & 3);
            af[i] = *(const bf16x8*)&shA[ra * 32 + ((lc ^ swa) << 3)];
            const int rb  = wn + i * 16 + lr;
            const int swb = (rb & 3) ^ ((rb >> 2) & 3);
            bfr[i] = *(const bf16x8*)&shB[rb * 32 + ((lc ^ swb) << 3)];
        }
        #pragma unroll
        for (int i = 0; i < 4; ++i)
            #pragma unroll
            for (int j = 0; j < 4; ++j)
                acc[i][j] = __builtin_amdgcn_mfma_f32_16x16x32_bf16(af[i], bfr[j], acc[i][j], 0, 0, 0);
    }

    #pragma unroll
    for (int i = 0; i < 4; ++i) {
        #pragma unroll
        for (int e = 0; e < 4; ++e) {
            const int m = m0 + wm + i * 16 + lc * 4 + e;   // C/D row
            float* crow;
            if (C1 != nullptr && m >= splitRow)
                crow = C1 + (long)bz * sC + (long)(m - splitRow) * ldc;
            else
                crow = C0 + (long)bz * sC + (long)m * ldc;
            const float bi = (EPI == 1) ? biasp[m - mro] : 0.f;
            #pragma unroll
            for (int j = 0; j < 4; ++j) {
                const int n = n0 + wn + j * 16 + lr;       // C/D col
                if (n < N2) {
                    float v = acc[i][j][e];
                    if (EPI == 1) {
                        const float t = v + bi;
                        v = fmaxf(t, 0.f) + log1pf(__expf(-fabsf(t)));
                    }
                    if (EPI == 2) atomicAdd(crow + n, v);
                    else          crow[n] = v;
                }
            }
        }
    }
}

// ---------------------------------------------------------------------------
// Depthwise causal conv (K=4) + bias + SiLU, 32x32 LDS tiles.
// ---------------------------------------------------------------------------
__global__ __launch_bounds__(256)
void conv_silu_t(const float* __restrict__ x, const float* __restrict__ cw,
                 const float* __restrict__ cb,
                 float* __restrict__ conv, u16* __restrict__ convT)
{
    __shared__ float xs_[32][36];   // [d][l0-3 .. l0+31]
    __shared__ float cs[32][33];    // [l][d]
    const int l0 = blockIdx.x * 32, d0 = blockIdx.y * 32, b = blockIdx.z;
    const int lx = threadIdx.x & 31, dy = threadIdx.x >> 5;

    #pragma unroll
    for (int r = 0; r < 4; ++r) {
        const int dd = dy + r * 8;
        const float* xr = x + ((long)b * cDM + d0 + dd) * cL;
        const int li = l0 - 3 + lx;
        xs_[dd][lx] = (li >= 0) ? xr[li] : 0.f;
        if (lx < 3) xs_[dd][32 + lx] = xr[l0 + 29 + lx];
    }
    __syncthreads();
    #pragma unroll
    for (int r = 0; r < 4; ++r) {
        const int dd = dy + r * 8;
        const int d = d0 + dd;
        const float w0 = cw[d*4], w1 = cw[d*4+1], w2 = cw[d*4+2], w3 = cw[d*4+3];
        float v = cb[d];
        v = fmaf(w0, xs_[dd][lx],     v);
        v = fmaf(w1, xs_[dd][lx + 1], v);
        v = fmaf(w2, xs_[dd][lx + 2], v);
        v = fmaf(w3, xs_[dd][lx + 3], v);
        const float s = v / (1.f + __expf(-v));   // SiLU
        conv[((long)b * cDM + d) * cL + l0 + lx] = s;
        cs[lx][dd] = s;
    }
    __syncthreads();
    #pragma unroll
    for (int r = 0; r < 4; ++r) {
        const int ll = dy + r * 8;
        convT[((long)b * cL + l0 + ll) * cDM + d0 + lx] = f2bf(cs[ll][lx]);
    }
}

// ---------------------------------------------------------------------------
// Chunked parallel scan, 3 phases. Chunk = 256 steps, 4 chunks per stream.
// Streams: (b, dir, d); state lane n = 0..15.
//
// scanA: per-chunk (Aprod_n, xfinal_n) from x0=0. grid (96, B, 2*4).
// scanB: serial compose over 4 chunks -> X0 per chunk. tiny.
// scanC: full scan per chunk seeded with X0, y output. grid (96, B, 2*4).
// ---------------------------------------------------------------------------
__global__ __launch_bounds__(256)
void scanA_kernel(const float* __restrict__ conv,
                  const float* __restrict__ delta_f,
                  const float* __restrict__ delta_b,
                  const float* __restrict__ ssms,
                  const float* __restrict__ Alog_f,
                  const float* __restrict__ Alog_b,
                  float* __restrict__ Ap_out, float* __restrict__ Xf_out)
{
    const int g = threadIdx.x >> 4, n = threadIdx.x & 15;
    const int d = blockIdx.x * 16 + g;
    const int b = blockIdx.y;
    const int z = blockIdx.z;           // dir*cCK + chunk
    const int dir = z >> 2, ck = z & 3;

    const float* delta = dir ? delta_b : delta_f;
    const float* Alog  = dir ? Alog_b  : Alog_f;
    const float a = -__expf(Alog[d * cN + n]);
    const int sofs = dir ? 128 : 48;

    const float* up = conv  + ((long)b * cDM + d) * cL;
    const float* dp = delta + ((long)b * cDM + d) * cL;
    const float* sp = ssms + (long)b * cL * cPS;

    const int t0c = ck * (cL / cCK);
    float xs = 0.f, Ap = 1.f;
    for (int c = 0; c < (cL / cCK) / 8; ++c) {     // 32 tiles of 8
        const int tt = t0c + c * 8;
        const int t8 = n & 7;
        const int lt = dir ? (cL - 1 - (tt + t8)) : (tt + t8);
        const float du_n = dp[lt];
        const float u_n  = up[lt];
        float B8[8];
        #pragma unroll
        for (int t = 0; t < 8; ++t) {
            const int l = dir ? (cL - 1 - (tt + t)) : (tt + t);
            B8[t] = sp[(long)l * cPS + sofs + n];
        }
        float dA[8];
        #pragma unroll
        for (int t = 0; t < 8; ++t) {
            const float dut = __shfl(du_n, t, 16);
            const float ut  = __shfl(u_n,  t, 16);
            dA[t] = __expf(dut * a);
            B8[t] = (dut * ut) * B8[t];
        }
        #pragma unroll
        for (int t = 0; t < 8; ++t) {
            xs = fmaf(dA[t], xs, B8[t]);   // serial (4cyc fmaf chain)
            Ap *= dA[t];                   // parallel serial chain
        }
    }
    const long idx = (((long)(b * 2 + dir) * cDM + d) * cCK + ck) * 16 + n;
    Ap_out[idx] = Ap;
    Xf_out[idx] = xs;
}

__global__ __launch_bounds__(256)
void scanB_kernel(const float* __restrict__ Ap, const float* __restrict__ Xf,
                  float* __restrict__ X0)
{
    const int gid = blockIdx.x * 256 + threadIdx.x;  // 2*B*DM*16 = 98304
    const int n = gid & 15;
    const long s = gid >> 4;                          // stream id
    float x0 = 0.f;
    #pragma unroll
    for (int c = 0; c < cCK; ++c) {
        const long idx = (s * cCK + c) * 16 + n;
        X0[idx] = x0;
        x0 = fmaf(Ap[idx], x0, Xf[idx]);
    }
}

// scanC staging: window = 32 steps, double-buffered.
#define C_STAGE_LOAD(w) do {                                                  \
    const int ta_ = tb0 + (w) * 32;                                           \
    const int lb_ = dir ? (cL - 1 - (ta_ + t_bc)) : (ta_ + t_bc);             \
    rbc = *(const float4*)&sp[(long)lb_ * cPS + sofs + cc0];                  \
    const int tu_ = ta_ + 2 * n;                                              \
    if (!dir) {                                                               \
        ru2 = *(const float2*)&up[tu_];                                       \
        rd2 = *(const float2*)&dp[tu_];                                       \
    } else {                                                                  \
        const float2 a_ = *(const float2*)&up[cL - 2 - tu_];                  \
        const float2 b_ = *(const float2*)&dp[cL - 2 - tu_];                  \
        ru2 = make_float2(a_.y, a_.x);                                        \
        rd2 = make_float2(b_.y, b_.x);                                        \
    }                                                                         \
} while (0)

#define C_STAGE_WRITE(bufi) do {                                              \
    *(float4*)&bcS[bufi][t_bc][cc0] = rbc;                                    \
    *(float2*)&dS[bufi][g][2 * n]   = rd2;                                    \
    *(float2*)&duuS[bufi][g][2 * n] = make_float2(rd2.x * ru2.x, rd2.y * ru2.y); \
} while (0)

__global__ __launch_bounds__(256, 6)
void scanC_kernel(const float* __restrict__ conv,
                  const float* __restrict__ gate,
                  const float* __restrict__ delta_f,
                  const float* __restrict__ delta_b,
                  const float* __restrict__ ssms,
                  const float* __restrict__ Alog_f,
                  const float* __restrict__ Alog_b,
                  const float* __restrict__ D_f, const float* __restrict__ D_b,
                  const float* __restrict__ X0,
                  u16* __restrict__ yf, u16* __restrict__ yb)
{
    __shared__ float bcS[2][32][33];   // [buf][t][c]; pad 33: conflict-free r/w
    __shared__ float dS[2][16][34];    // [buf][ch][t]
    __shared__ float duuS[2][16][34];  // [buf][ch][t] = delta*u

    const int tid = threadIdx.x;
    const int g = tid >> 4, n = tid & 15;
    const int d = blockIdx.x * 16 + g;
    const int b = blockIdx.y;
    const int z = blockIdx.z;
    const int dir = z >> 2, ck = z & 3;

    const float* delta = dir ? delta_b : delta_f;
    const float* Alog  = dir ? Alog_b  : Alog_f;
    const float  Dd    = dir ? D_b[d]  : D_f[d];
    u16*         yout  = dir ? yb      : yf;
    const float  a     = -__expf(Alog[d * cN + n]);
    const int    sofs  = dir ? 128 : 48;

    const int t_bc = tid >> 3;          // 0..31: bc row staged by this thread
    const int cc0  = (tid & 7) << 2;    // 0,4,..,28: float4 cols
    const int tb0  = ck * (cL / cCK);

    const float* up = conv  + ((long)b * cDM + d) * cL;
    const float* gp = gate  + ((long)b * cDM + d) * cL;
    const float* dp = delta + ((long)b * cDM + d) * cL;
    const float* sp = ssms + (long)b * cL * cPS;

    float xs = X0[(((long)(b * 2 + dir) * cDM + d) * cCK + ck) * 16 + n];

    float4 rbc; float2 ru2, rd2;
    C_STAGE_LOAD(0);
    C_STAGE_WRITE(0);
    __syncthreads();

    for (int w = 0; w < 8; ++w) {               // 8 windows of 32
        const int cur = w & 1;
        if (w < 7) C_STAGE_LOAD(w + 1);         // overlaps compute

        for (int s = 0; s < 4; ++s) {           // 4 sub-tiles of 8
            float dA8[8], dBu8[8], C8[8];
            #pragma unroll
            for (int k = 0; k < 8; ++k) {
                const int t = s * 8 + k;
                dA8[k]  = __expf(dS[cur][g][t] * a);
                dBu8[k] = duuS[cur][g][t] * bcS[cur][t][n];
                C8[k]   = bcS[cur][t][16 + n];
            }
            float yo = 0.f;
            #pragma unroll
            for (int k = 0; k < 8; ++k) {
                xs = fmaf(dA8[k], xs, dBu8[k]);   // only serial dependence
                float y = xs * C8[k];
                y += __shfl_xor(y, 1);
                y += __shfl_xor(y, 2);
                y += __shfl_xor(y, 4);
                y += __shfl_xor(y, 8);
                if (n == k) yo = y;
            }
            if (n < 8) {
                const int wt = tb0 + w * 32 + s * 8 + n;
                const int l  = dir ? (cL - 1 - wt) : wt;
                const float uu = up[l];
                const float gv = gp[l];
                const float val = (yo + uu * Dd) * (gv / (1.f + __expf(-gv)));
                yout[((long)b * cL + l) * cDM + d] = f2bf(val);
            }
        }

        if (w < 7) C_STAGE_WRITE(cur ^ 1);
        __syncthreads();
    }
}

// ---------------------------------------------------------------------------
extern "C" void kernel_launch(void* const* d_in, const int* in_sizes, int n_in,
                              void* d_out, int out_size, void* d_ws, size_t ws_size,
                              hipStream_t stream)
{
    const float* hid   = (const float*)d_in[0];   // (B,L,H)
    const float* inw   = (const float*)d_in[1];   // (2DM,H)
    const float* convw = (const float*)d_in[2];   // (DM,K)
    const float* convb = (const float*)d_in[3];   // (DM)
    const float* xpw   = (const float*)d_in[4];   // (80,DM)
    const float* dtw   = (const float*)d_in[5];   // (DM,R)
    const float* dtb   = (const float*)d_in[6];   // (DM)
    const float* xpbw  = (const float*)d_in[7];
    const float* dtbw  = (const float*)d_in[8];
    const float* dtbb  = (const float*)d_in[9];
    const float* Alog  = (const float*)d_in[10];  // (DM,16)
    const float* Alogb = (const float*)d_in[11];
    const float* Dv    = (const float*)d_in[12];
    const float* Dbv   = (const float*)d_in[13];
    const float* outw  = (const float*)d_in[14];  // (H,DM)
    float* out = (float*)d_out;                   // (B,L,H)

    float* ws = (float*)d_ws;
    const long S = (long)cB * cDM * cL;           // 3,145,728
    float* xbuf   = ws;                // x, then delta_f
    float* gate   = ws + S;
    float* conv   = ws + 2 * S;        // u fp32 (b,d,l)
    float* deltab = ws + 3 * S;
    float* ssms   = ws + 4 * S;        // (B,L,160) fp32
    u16* up0      = (u16*)(ssms + (long)cB * cL * cPS);
    u16* convT_b  = up0;                              // S u16; later yf
    u16* ts2_b    = up0 + S;                          // 2*B*L*64 = 262,144
    u16* xpw2_b   = ts2_b + (long)2 * cB * cL * 64;   // 160*DM stacked
    u16* dtw2_b   = xpw2_b + (long)cPS * cDM;         // 2*DM*64 stacked
    u16* outw_b   = dtw2_b + (long)2 * cDM * 64;      // H*DM
    u16* pool2    = outw_b + (long)cH * cDM;          // 3,932,160 u16
    u16* inw_b    = pool2;                            // 2*DM*H (phase 1)
    u16* hid_b    = pool2 + (long)2 * cDM * cH;       // B*L*H  (phase 1)
    u16* yf_b     = convT_b;                          // phase 2 (after x_proj)
    u16* yb_b     = pool2;                            // phase 2 (after in_proj)
    // scan chunk summaries (after everything else)
    const long nSum = (long)2 * cB * cDM * cCK * 16;  // 393,216 floats
    float* sumAp  = (float*)(pool2 + 3932160);
    float* sumXf  = sumAp + nSum;
    float* sumX0  = sumXf + nSum;

    const dim3 blk(256);

    // 0. dtype converts (weights stacked for fused GEMMs)
    f2b_kernel<<<1024, blk, 0, stream>>>(hid,  hid_b,  (long)cB * cL * cH);
    f2b_kernel<<<1024, blk, 0, stream>>>(inw,  inw_b,  (long)2 * cDM * cH);
    f2b_kernel<<<480,  blk, 0, stream>>>(xpw,  xpw2_b, (long)80 * cDM);
    f2b_kernel<<<480,  blk, 0, stream>>>(xpbw, xpw2_b + (long)80 * cDM, (long)80 * cDM);
    f2b_kernel<<<1024, blk, 0, stream>>>(outw, outw_b, (long)cH * cDM);
    padw_kernel<<<384, blk, 0, stream>>>(dtw,  dtw2_b,  cDM);
    padw_kernel<<<384, blk, 0, stream>>>(dtbw, dtw2_b + (long)cDM * 64, cDM);

    // split-K atomic targets must be zeroed
    hipMemsetAsync(ssms, 0, (long)cB * cL * cPS * sizeof(float), stream);
    hipMemsetAsync(out, 0, (long)out_size * sizeof(float), stream);

    // 1. in_proj (M=3072, N=L, K=H), split x | gate
    gemm_mfma<0><<<dim3(cL / 128, (2 * cDM) / 128, cB), blk, 0, stream>>>(
        inw_b, hid_b, nullptr, xbuf, gate, nullptr, nullptr,
        cL, cH, cH, cH, cL, 0L, (long)cL * cH, (long)cDM * cL, cDM, 1);

    // 2. causal conv + SiLU (tiled; both outputs coalesced)
    conv_silu_t<<<dim3(cL / 32, cDM / 32, cB), blk, 0, stream>>>(
        xbuf, convw, convb, conv, convT_b);

    // 3. fused x_proj fwd+bwd: M=L, N=160, K=DM, split-K=8
    gemm_mfma<2><<<dim3(2, cL / 128, cB * 8), blk, 0, stream>>>(
        convT_b, xpw2_b, nullptr, ssms, nullptr, nullptr, nullptr,
        cPS, cDM, cDM, cDM, cPS, (long)cL * cDM, 0L, (long)cL * cPS, 1 << 30, 8);

    // 4. ts slices -> padded bf16 (2,B,L,64)
    tspad_kernel<<<1024, blk, 0, stream>>>(ssms, ts2_b);

    // 5. fused delta fwd+bwd: M=3072, N=L, K=64; B/bias switch at m=1536
    gemm_mfma<1><<<dim3(cL / 128, (2 * cDM) / 128, cB), blk, 0, stream>>>(
        dtw2_b, ts2_b, ts2_b + (long)cB * cL * 64,
        xbuf /*delta_f*/, deltab, dtb, dtbb,
        cL, 64, 64, 64, cL, 0L, (long)cL * 64, (long)cDM * cL, cDM, 1);

    // 6. chunked parallel scan: A (local summaries) -> B (compose) -> C (full)
    scanA_kernel<<<dim3(cDM / 16, cB, 2 * cCK), blk, 0, stream>>>(
        conv, xbuf /*delta_f*/, deltab, ssms, Alog, Alogb, sumAp, sumXf);
    scanB_kernel<<<dim3((int)(nSum / 256)), blk, 0, stream>>>(sumAp, sumXf, sumX0);
    scanC_kernel<<<dim3(cDM / 16, cB, 2 * cCK), blk, 0, stream>>>(
        conv, gate, xbuf /*delta_f*/, deltab, ssms,
        Alog, Alogb, Dv, Dbv, sumX0, yf_b, yb_b);

    // 7. combine: yf += yb (in place, bf16, 16B/thread)
    comb_kernel<<<(int)(S / 8 / 256), blk, 0, stream>>>(yf_b, yb_b, S / 8);

    // 8. out_proj: M=L, N=H, K=DM, split-K=2 (out zeroed above)
    gemm_mfma<2><<<dim3(cH / 128, cL / 128, cB * 2), blk, 0, stream>>>(
        yf_b, outw_b, nullptr, out, nullptr, nullptr, nullptr,
        cH, cDM, cDM, cDM, cH, (long)cL * cDM, 0L, (long)cL * cH, 1 << 30, 2);
}

// Round 7
// 323.198 us; speedup vs baseline: 1.0727x; 1.0727x over previous
//
#include <hip/hip_runtime.h>
#include <math.h>

// Problem constants
constexpr int cH  = 768;
constexpr int cDM = 1536;
constexpr int cN  = 16;
constexpr int cR  = 48;
constexpr int cB  = 2;
constexpr int cL  = 1024;
constexpr int cPS = 160;  // stacked ssm row: [fwd 80 | bwd 80]
constexpr int cCK = 8;    // scan chunks (chunk length = cL/cCK = 128)

typedef unsigned short u16;
typedef __attribute__((ext_vector_type(8))) short bf16x8;
typedef __attribute__((ext_vector_type(4))) float f32x4;

__device__ __forceinline__ u16 f2bf(float f) {
    unsigned u = __float_as_uint(f);
    u += 0x7FFF + ((u >> 16) & 1);          // RNE
    return (u16)(u >> 16);
}
__device__ __forceinline__ float bf2f(u16 h) {
    return __uint_as_float((unsigned)h << 16);
}

// 16-lane butterfly sum via DPP (VALU only, no LDS pipe):
// xor1 (quad_perm 0xB1), xor2 (0x4E), xor7 (row_half_mirror 0x141),
// xor15 (row_mirror 0x140). Every lane of the 16-row ends with the sum.
__device__ __forceinline__ float row16_sum(float y) {
    int v;
    v = __builtin_amdgcn_update_dpp(0, __float_as_int(y), 0xB1, 0xF, 0xF, true);
    y += __int_as_float(v);
    v = __builtin_amdgcn_update_dpp(0, __float_as_int(y), 0x4E, 0xF, 0xF, true);
    y += __int_as_float(v);
    v = __builtin_amdgcn_update_dpp(0, __float_as_int(y), 0x141, 0xF, 0xF, true);
    y += __int_as_float(v);
    v = __builtin_amdgcn_update_dpp(0, __float_as_int(y), 0x140, 0xF, 0xF, true);
    y += __int_as_float(v);
    return y;
}

// ---------------------------------------------------------------------------
// small helpers
// ---------------------------------------------------------------------------
__global__ __launch_bounds__(256)
void f2b_kernel(const float* __restrict__ in, u16* __restrict__ out, long n) {
    for (long i = (long)blockIdx.x * 256 + threadIdx.x; i < n; i += (long)gridDim.x * 256)
        out[i] = f2bf(in[i]);
}

__global__ __launch_bounds__(256)
void padw_kernel(const float* __restrict__ in, u16* __restrict__ out, int rows) {
    int i = blockIdx.x * 256 + threadIdx.x;
    if (i >= rows * 64) return;
    int r = i >> 6, k = i & 63;
    out[i] = (k < cR) ? f2bf(in[r * cR + k]) : (u16)0;
}

__global__ __launch_bounds__(256)
void tspad_kernel(const float* __restrict__ ssms, u16* __restrict__ out) {
    int i = blockIdx.x * 256 + threadIdx.x;    // exactly 2*B*L*64 = 262144
    int dirsel = i >> 17;
    int rem = i & 131071;
    int bl = rem >> 6, k = rem & 63;
    out[i] = (k < cR) ? f2bf(ssms[(long)bl * cPS + dirsel * 80 + k]) : (u16)0;
}

__global__ __launch_bounds__(256)
void comb_kernel(u16* __restrict__ yf, const u16* __restrict__ yb, long n8) {
    long i = (long)blockIdx.x * 256 + threadIdx.x;
    if (i >= n8) return;
    uint4 av = ((uint4*)yf)[i];
    uint4 bv = ((const uint4*)yb)[i];
    unsigned* ap = (unsigned*)&av;
    unsigned* bp = (unsigned*)&bv;
    #pragma unroll
    for (int j = 0; j < 4; ++j) {
        const float lo = bf2f((u16)(ap[j] & 0xffff)) + bf2f((u16)(bp[j] & 0xffff));
        const float hi = bf2f((u16)(ap[j] >> 16))    + bf2f((u16)(bp[j] >> 16));
        ap[j] = (unsigned)f2bf(lo) | ((unsigned)f2bf(hi) << 16);
    }
    ((uint4*)yf)[i] = av;
}

// ---------------------------------------------------------------------------
// bf16 MFMA NT GEMM, 2-phase software pipeline (T3-minimum):
// double-buffered LDS; issue next tile's global_load_lds BEFORE computing
// current tile; single vmcnt drain (inside __syncthreads) per K-iter.
// ---------------------------------------------------------------------------
__device__ __forceinline__ void gld_lds16(const u16* g, u16* l) {
    __builtin_amdgcn_global_load_lds(
        (const __attribute__((address_space(1))) unsigned int*)g,
        (__attribute__((address_space(3))) unsigned int*)l, 16, 0, 0);
}

#define GSTAGE(buf, k0) do {                                                  \
    _Pragma("unroll")                                                         \
    for (int h = 0; h < 2; ++h) {                                             \
        const int qq = wid * 2 + h;                                           \
        const int rr = qq * 16 + (lane >> 2);                                 \
        const int sw = (rr & 3) ^ ((rr >> 2) & 3);                            \
        const int kg = (k0) + (((lane & 3) ^ sw) << 3);                       \
        gld_lds16(Ab + (long)(m0 + rr) * lda + kg, &shA[buf][qq * 512]);      \
        int nr = n0 + rr; if (nr > N2 - 1) nr = N2 - 1;                       \
        gld_lds16(Bb + (long)nr * ldb + kg, &shB[buf][qq * 512]);             \
    }                                                                         \
} while (0)

template<int EPI>
__global__ __launch_bounds__(256, 3)
void gemm_mfma(const u16* __restrict__ A, const u16* __restrict__ B,
               const u16* __restrict__ B_hi,
               float* __restrict__ C0, float* __restrict__ C1,
               const float* __restrict__ bias, const float* __restrict__ bias_hi,
               int N2, int Kd, int lda, int ldb, int ldc,
               long sA, long sB, long sC, int splitRow, int kspl)
{
    __shared__ __align__(16) u16 shA[2][4096];   // [buf][128][32] chunk-swizzled
    __shared__ __align__(16) u16 shB[2][4096];
    const int tid  = threadIdx.x;
    const int wid  = tid >> 6, lane = tid & 63;
    const int lr   = lane & 15, lc = lane >> 4;
    const int z    = blockIdx.z;
    const int bz   = z / kspl, ks = z % kspl;
    const int kpc  = Kd / kspl;
    const int kbeg = ks * kpc;
    const int nt   = kpc / 32;
    const int n0 = blockIdx.x * 128, m0 = blockIdx.y * 128;

    const u16* Bsel = (B_hi != nullptr && m0 >= splitRow) ? B_hi : B;
    const float* biasp = (bias_hi != nullptr && m0 >= splitRow) ? bias_hi : bias;
    const int mro = (bias_hi != nullptr && m0 >= splitRow) ? splitRow : 0;

    const u16* Ab = A + (long)bz * sA;
    const u16* Bb = Bsel + (long)bz * sB;
    const int wm = (wid >> 1) * 64, wn = (wid & 1) * 64;

    f32x4 acc[4][4] = {};

    GSTAGE(0, kbeg);                       // prologue
    __syncthreads();

    int cur = 0;
    for (int t = 0; t < nt; ++t) {
        if (t + 1 < nt) GSTAGE(cur ^ 1, kbeg + (t + 1) * 32);  // prefetch
        bf16x8 af[4], bfr[4];
        #pragma unroll
        for (int i = 0; i < 4; ++i) {
            const int ra  = wm + i * 16 + lr;
            const int swa = (ra & 3) ^ ((ra >> 2) & 3);
            af[i] = *(const bf16x8*)&shA[cur][ra * 32 + ((lc ^ swa) << 3)];
            const int rb  = wn + i * 16 + lr;
            const int swb = (rb & 3) ^ ((rb >> 2) & 3);
            bfr[i] = *(const bf16x8*)&shB[cur][rb * 32 + ((lc ^ swb) << 3)];
        }
        #pragma unroll
        for (int i = 0; i < 4; ++i)
            #pragma unroll
            for (int j = 0; j < 4; ++j)
                acc[i][j] = __builtin_amdgcn_mfma_f32_16x16x32_bf16(af[i], bfr[j], acc[i][j], 0, 0, 0);
        __syncthreads();                   // drains prefetch vmcnt + joins
        cur ^= 1;
    }

    #pragma unroll
    for (int i = 0; i < 4; ++i) {
        #pragma unroll
        for (int e = 0; e < 4; ++e) {
            const int m = m0 + wm + i * 16 + lc * 4 + e;   // C/D row
            float* crow;
            if (C1 != nullptr && m >= splitRow)
                crow = C1 + (long)bz * sC + (long)(m - splitRow) * ldc;
            else
                crow = C0 + (long)bz * sC + (long)m * ldc;
            const float bi = (EPI == 1) ? biasp[m - mro] : 0.f;
            #pragma unroll
            for (int j = 0; j < 4; ++j) {
                const int n = n0 + wn + j * 16 + lr;       // C/D col
                if (n < N2) {
                    float v = acc[i][j][e];
                    if (EPI == 1) {
                        const float t2 = v + bi;
                        v = fmaxf(t2, 0.f) + log1pf(__expf(-fabsf(t2)));
                    }
                    if (EPI == 2) atomicAdd(crow + n, v);
                    else          crow[n] = v;
                }
            }
        }
    }
}

// ---------------------------------------------------------------------------
// Depthwise causal conv (K=4) + bias + SiLU, 32x32 LDS tiles.
// ---------------------------------------------------------------------------
__global__ __launch_bounds__(256)
void conv_silu_t(const float* __restrict__ x, const float* __restrict__ cw,
                 const float* __restrict__ cb,
                 float* __restrict__ conv, u16* __restrict__ convT)
{
    __shared__ float xs_[32][36];   // [d][l0-3 .. l0+31]
    __shared__ float cs[32][33];    // [l][d]
    const int l0 = blockIdx.x * 32, d0 = blockIdx.y * 32, b = blockIdx.z;
    const int lx = threadIdx.x & 31, dy = threadIdx.x >> 5;

    #pragma unroll
    for (int r = 0; r < 4; ++r) {
        const int dd = dy + r * 8;
        const float* xr = x + ((long)b * cDM + d0 + dd) * cL;
        const int li = l0 - 3 + lx;
        xs_[dd][lx] = (li >= 0) ? xr[li] : 0.f;
        if (lx < 3) xs_[dd][32 + lx] = xr[l0 + 29 + lx];
    }
    __syncthreads();
    #pragma unroll
    for (int r = 0; r < 4; ++r) {
        const int dd = dy + r * 8;
        const int d = d0 + dd;
        const float w0 = cw[d*4], w1 = cw[d*4+1], w2 = cw[d*4+2], w3 = cw[d*4+3];
        float v = cb[d];
        v = fmaf(w0, xs_[dd][lx],     v);
        v = fmaf(w1, xs_[dd][lx + 1], v);
        v = fmaf(w2, xs_[dd][lx + 2], v);
        v = fmaf(w3, xs_[dd][lx + 3], v);
        const float s = v / (1.f + __expf(-v));   // SiLU
        conv[((long)b * cDM + d) * cL + l0 + lx] = s;
        cs[lx][dd] = s;
    }
    __syncthreads();
    #pragma unroll
    for (int r = 0; r < 4; ++r) {
        const int ll = dy + r * 8;
        convT[((long)b * cL + l0 + ll) * cDM + d0 + lx] = f2bf(cs[ll][lx]);
    }
}

// ---------------------------------------------------------------------------
// Chunked parallel scan, 3 phases. Chunk = 128 steps, 8 chunks per stream.
// grid (96, B, 2*8) = 3072 blocks for A and C (12 blocks/CU).
// All LDS tiles transposed to [c][t] (stride 36): per-8-step subtile each
// lane reads 2x ds_read_b128; no cross-lane shuffles anywhere (DPP reduce).
// ---------------------------------------------------------------------------

// common staging (window = 32 steps, double-buffered).
// thread roles: t_bc = tid>>3 (0..31 source step), cc0 = (tid&7)*4 (col base)
#define SC_LOAD(w) do {                                                       \
    const int ta_ = tb0 + (w) * 32;                                           \
    const int lb_ = dir ? (cL - 1 - (ta_ + t_bc)) : (ta_ + t_bc);             \
    rbc = *(const float4*)&sp[(long)lb_ * cPS + sofs + cc0];                  \
    const int tu_ = ta_ + 2 * n;                                              \
    if (!dir) {                                                               \
        ru2 = *(const float2*)&up[tu_];                                       \
        rd2 = *(const float2*)&dp[tu_];                                       \
    } else {                                                                  \
        const float2 a_ = *(const float2*)&up[cL - 2 - tu_];                  \
        const float2 b_ = *(const float2*)&dp[cL - 2 - tu_];                  \
        ru2 = make_float2(a_.y, a_.x);                                        \
        rd2 = make_float2(b_.y, b_.x);                                        \
    }                                                                         \
} while (0)

#define SC_WRITE(bufi) do {                                                   \
    bcS[bufi][cc0 + 0][t_bc] = rbc.x;                                         \
    bcS[bufi][cc0 + 1][t_bc] = rbc.y;                                         \
    bcS[bufi][cc0 + 2][t_bc] = rbc.z;                                         \
    bcS[bufi][cc0 + 3][t_bc] = rbc.w;                                         \
    *(float2*)&dS[bufi][g][2 * n]   = rd2;                                    \
    *(float2*)&duuS[bufi][g][2 * n] = make_float2(rd2.x * ru2.x, rd2.y * ru2.y); \
} while (0)

// scanA: per-chunk (Aprod_n, xfinal_n) from x0=0. Lane-local math only.
__global__ __launch_bounds__(256)
void scanA_kernel(const float* __restrict__ conv,
                  const float* __restrict__ delta_f,
                  const float* __restrict__ delta_b,
                  const float* __restrict__ ssms,
                  const float* __restrict__ Alog_f,
                  const float* __restrict__ Alog_b,
                  float* __restrict__ Ap_out, float* __restrict__ Xf_out)
{
    __shared__ float bcS[2][32][36];   // [buf][c][t] (only c<16=B used here... stage all 32)
    __shared__ float dS[2][16][36];
    __shared__ float duuS[2][16][36];

    const int tid = threadIdx.x;
    const int g = tid >> 4, n = tid & 15;
    const int d = blockIdx.x * 16 + g;
    const int b = blockIdx.y;
    const int z = blockIdx.z;
    const int dir = z >> 3, ck = z & 7;

    const float* delta = dir ? delta_b : delta_f;
    const float* Alog  = dir ? Alog_b  : Alog_f;
    const float a = -__expf(Alog[d * cN + n]);
    const int sofs = dir ? 128 : 48;

    const int t_bc = tid >> 3;
    const int cc0  = (tid & 7) << 2;
    const int tb0  = ck * (cL / cCK);

    const float* up = conv  + ((long)b * cDM + d) * cL;
    const float* dp = delta + ((long)b * cDM + d) * cL;
    const float* sp = ssms + (long)b * cL * cPS;

    float4 rbc; float2 ru2, rd2;
    SC_LOAD(0);
    SC_WRITE(0);
    __syncthreads();

    float xs = 0.f, Ap = 1.f;
    for (int w = 0; w < (cL / cCK) / 32; ++w) {      // 4 windows of 32
        const int cur = w & 1;
        if (w < (cL / cCK) / 32 - 1) SC_LOAD(w + 1);

        #pragma unroll
        for (int s = 0; s < 4; ++s) {
            const int t0 = s * 8;
            const float4 b0  = *(const float4*)&bcS[cur][n][t0];
            const float4 b1  = *(const float4*)&bcS[cur][n][t0 + 4];
            const float4 dd0 = *(const float4*)&dS[cur][g][t0];
            const float4 dd1 = *(const float4*)&dS[cur][g][t0 + 4];
            const float4 uu0 = *(const float4*)&duuS[cur][g][t0];
            const float4 uu1 = *(const float4*)&duuS[cur][g][t0 + 4];
            float dA[8], dBu[8];
            dA[0]=__expf(dd0.x*a); dA[1]=__expf(dd0.y*a); dA[2]=__expf(dd0.z*a); dA[3]=__expf(dd0.w*a);
            dA[4]=__expf(dd1.x*a); dA[5]=__expf(dd1.y*a); dA[6]=__expf(dd1.z*a); dA[7]=__expf(dd1.w*a);
            dBu[0]=uu0.x*b0.x; dBu[1]=uu0.y*b0.y; dBu[2]=uu0.z*b0.z; dBu[3]=uu0.w*b0.w;
            dBu[4]=uu1.x*b1.x; dBu[5]=uu1.y*b1.y; dBu[6]=uu1.z*b1.z; dBu[7]=uu1.w*b1.w;
            #pragma unroll
            for (int k = 0; k < 8; ++k) {
                xs = fmaf(dA[k], xs, dBu[k]);
                Ap *= dA[k];
            }
        }
        if (w < (cL / cCK) / 32 - 1) SC_WRITE(cur ^ 1);
        __syncthreads();
    }
    const long idx = (((long)(b * 2 + dir) * cDM + d) * cCK + ck) * 16 + n;
    Ap_out[idx] = Ap;
    Xf_out[idx] = xs;
}

__global__ __launch_bounds__(256)
void scanB_kernel(const float* __restrict__ Ap, const float* __restrict__ Xf,
                  float* __restrict__ X0)
{
    const int gid = blockIdx.x * 256 + threadIdx.x;  // 2*B*DM*16 = 98304
    const int n = gid & 15;
    const long s = gid >> 4;                          // stream id
    float x0 = 0.f;
    #pragma unroll
    for (int c = 0; c < cCK; ++c) {
        const long idx = (s * cCK + c) * 16 + n;
        X0[idx] = x0;
        x0 = fmaf(Ap[idx], x0, Xf[idx]);
    }
}

// scanC: full scan per chunk seeded with X0; DPP reduce; y output.
__global__ __launch_bounds__(256)
void scanC_kernel(const float* __restrict__ conv,
                  const float* __restrict__ gate,
                  const float* __restrict__ delta_f,
                  const float* __restrict__ delta_b,
                  const float* __restrict__ ssms,
                  const float* __restrict__ Alog_f,
                  const float* __restrict__ Alog_b,
                  const float* __restrict__ D_f, const float* __restrict__ D_b,
                  const float* __restrict__ X0,
                  u16* __restrict__ yf, u16* __restrict__ yb)
{
    __shared__ float bcS[2][32][36];   // [buf][c][t]: c 0-15 B_n, 16-31 C_n
    __shared__ float dS[2][16][36];    // [buf][ch][t]
    __shared__ float duuS[2][16][36];  // [buf][ch][t] = delta*u

    const int tid = threadIdx.x;
    const int g = tid >> 4, n = tid & 15;
    const int d = blockIdx.x * 16 + g;
    const int b = blockIdx.y;
    const int z = blockIdx.z;
    const int dir = z >> 3, ck = z & 7;

    const float* delta = dir ? delta_b : delta_f;
    const float* Alog  = dir ? Alog_b  : Alog_f;
    const float  Dd    = dir ? D_b[d]  : D_f[d];
    u16*         yout  = dir ? yb      : yf;
    const float  a     = -__expf(Alog[d * cN + n]);
    const int    sofs  = dir ? 128 : 48;

    const int t_bc = tid >> 3;
    const int cc0  = (tid & 7) << 2;
    const int tb0  = ck * (cL / cCK);

    const float* up = conv  + ((long)b * cDM + d) * cL;
    const float* gp = gate  + ((long)b * cDM + d) * cL;
    const float* dp = delta + ((long)b * cDM + d) * cL;
    const float* sp = ssms + (long)b * cL * cPS;

    float xs = X0[(((long)(b * 2 + dir) * cDM + d) * cCK + ck) * 16 + n];

    float4 rbc; float2 ru2, rd2;
    SC_LOAD(0);
    SC_WRITE(0);
    __syncthreads();

    for (int w = 0; w < (cL / cCK) / 32; ++w) {      // 4 windows of 32
        const int cur = w & 1;
        if (w < (cL / cCK) / 32 - 1) SC_LOAD(w + 1);

        #pragma unroll
        for (int s = 0; s < 4; ++s) {
            const int t0 = s * 8;
            const float4 b0  = *(const float4*)&bcS[cur][n][t0];
            const float4 b1  = *(const float4*)&bcS[cur][n][t0 + 4];
            const float4 c0  = *(const float4*)&bcS[cur][16 + n][t0];
            const float4 c1  = *(const float4*)&bcS[cur][16 + n][t0 + 4];
            const float4 dd0 = *(const float4*)&dS[cur][g][t0];
            const float4 dd1 = *(const float4*)&dS[cur][g][t0 + 4];
            const float4 uu0 = *(const float4*)&duuS[cur][g][t0];
            const float4 uu1 = *(const float4*)&duuS[cur][g][t0 + 4];
            float dA[8], dBu[8], C8[8];
            dA[0]=__expf(dd0.x*a); dA[1]=__expf(dd0.y*a); dA[2]=__expf(dd0.z*a); dA[3]=__expf(dd0.w*a);
            dA[4]=__expf(dd1.x*a); dA[5]=__expf(dd1.y*a); dA[6]=__expf(dd1.z*a); dA[7]=__expf(dd1.w*a);
            dBu[0]=uu0.x*b0.x; dBu[1]=uu0.y*b0.y; dBu[2]=uu0.z*b0.z; dBu[3]=uu0.w*b0.w;
            dBu[4]=uu1.x*b1.x; dBu[5]=uu1.y*b1.y; dBu[6]=uu1.z*b1.z; dBu[7]=uu1.w*b1.w;
            C8[0]=c0.x; C8[1]=c0.y; C8[2]=c0.z; C8[3]=c0.w;
            C8[4]=c1.x; C8[5]=c1.y; C8[6]=c1.z; C8[7]=c1.w;

            float yo = 0.f;
            #pragma unroll
            for (int k = 0; k < 8; ++k) {
                xs = fmaf(dA[k], xs, dBu[k]);        // only serial dependence
                const float y = row16_sum(xs * C8[k]);  // DPP, VALU-only
                if (n == k) yo = y;
            }
            if (n < 8) {
                const int wt = tb0 + w * 32 + t0 + n;
                const int l  = dir ? (cL - 1 - wt) : wt;
                const float uu = up[l];
                const float gv = gp[l];
                const float val = (yo + uu * Dd) * (gv / (1.f + __expf(-gv)));
                yout[((long)b * cL + l) * cDM + d] = f2bf(val);
            }
        }
        if (w < (cL / cCK) / 32 - 1) SC_WRITE(cur ^ 1);
        __syncthreads();
    }
}

// ---------------------------------------------------------------------------
extern "C" void kernel_launch(void* const* d_in, const int* in_sizes, int n_in,
                              void* d_out, int out_size, void* d_ws, size_t ws_size,
                              hipStream_t stream)
{
    const float* hid   = (const float*)d_in[0];   // (B,L,H)
    const float* inw   = (const float*)d_in[1];   // (2DM,H)
    const float* convw = (const float*)d_in[2];   // (DM,K)
    const float* convb = (const float*)d_in[3];   // (DM)
    const float* xpw   = (const float*)d_in[4];   // (80,DM)
    const float* dtw   = (const float*)d_in[5];   // (DM,R)
    const float* dtb   = (const float*)d_in[6];   // (DM)
    const float* xpbw  = (const float*)d_in[7];
    const float* dtbw  = (const float*)d_in[8];
    const float* dtbb  = (const float*)d_in[9];
    const float* Alog  = (const float*)d_in[10];  // (DM,16)
    const float* Alogb = (const float*)d_in[11];
    const float* Dv    = (const float*)d_in[12];
    const float* Dbv   = (const float*)d_in[13];
    const float* outw  = (const float*)d_in[14];  // (H,DM)
    float* out = (float*)d_out;                   // (B,L,H)

    float* ws = (float*)d_ws;
    const long S = (long)cB * cDM * cL;           // 3,145,728
    float* xbuf   = ws;                // x, then delta_f
    float* gate   = ws + S;
    float* conv   = ws + 2 * S;        // u fp32 (b,d,l)
    float* deltab = ws + 3 * S;
    float* ssms   = ws + 4 * S;        // (B,L,160) fp32
    u16* up0      = (u16*)(ssms + (long)cB * cL * cPS);
    u16* convT_b  = up0;                              // S u16; later yf
    u16* ts2_b    = up0 + S;                          // 2*B*L*64 = 262,144
    u16* xpw2_b   = ts2_b + (long)2 * cB * cL * 64;   // 160*DM stacked
    u16* dtw2_b   = xpw2_b + (long)cPS * cDM;         // 2*DM*64 stacked
    u16* outw_b   = dtw2_b + (long)2 * cDM * 64;      // H*DM
    u16* pool2    = outw_b + (long)cH * cDM;          // 3,932,160 u16
    u16* inw_b    = pool2;                            // 2*DM*H (phase 1)
    u16* hid_b    = pool2 + (long)2 * cDM * cH;       // B*L*H  (phase 1)
    u16* yf_b     = convT_b;                          // phase 2 (after x_proj)
    u16* yb_b     = pool2;                            // phase 2 (after in_proj)
    // scan chunk summaries
    const long nSum = (long)2 * cB * cDM * cCK * 16;  // 786,432 floats
    float* sumAp  = (float*)(pool2 + 3932160);
    float* sumXf  = sumAp + nSum;
    float* sumX0  = sumXf + nSum;

    const dim3 blk(256);

    // 0. dtype converts (weights stacked for fused GEMMs)
    f2b_kernel<<<1024, blk, 0, stream>>>(hid,  hid_b,  (long)cB * cL * cH);
    f2b_kernel<<<1024, blk, 0, stream>>>(inw,  inw_b,  (long)2 * cDM * cH);
    f2b_kernel<<<480,  blk, 0, stream>>>(xpw,  xpw2_b, (long)80 * cDM);
    f2b_kernel<<<480,  blk, 0, stream>>>(xpbw, xpw2_b + (long)80 * cDM, (long)80 * cDM);
    f2b_kernel<<<1024, blk, 0, stream>>>(outw, outw_b, (long)cH * cDM);
    padw_kernel<<<384, blk, 0, stream>>>(dtw,  dtw2_b,  cDM);
    padw_kernel<<<384, blk, 0, stream>>>(dtbw, dtw2_b + (long)cDM * 64, cDM);

    // split-K atomic targets must be zeroed
    hipMemsetAsync(ssms, 0, (long)cB * cL * cPS * sizeof(float), stream);
    hipMemsetAsync(out, 0, (long)out_size * sizeof(float), stream);

    // 1. in_proj (M=3072, N=L, K=H), split x | gate
    gemm_mfma<0><<<dim3(cL / 128, (2 * cDM) / 128, cB), blk, 0, stream>>>(
        inw_b, hid_b, nullptr, xbuf, gate, nullptr, nullptr,
        cL, cH, cH, cH, cL, 0L, (long)cL * cH, (long)cDM * cL, cDM, 1);

    // 2. causal conv + SiLU (tiled; both outputs coalesced)
    conv_silu_t<<<dim3(cL / 32, cDM / 32, cB), blk, 0, stream>>>(
        xbuf, convw, convb, conv, convT_b);

    // 3. fused x_proj fwd+bwd: M=L, N=160, K=DM, split-K=8
    gemm_mfma<2><<<dim3(2, cL / 128, cB * 8), blk, 0, stream>>>(
        convT_b, xpw2_b, nullptr, ssms, nullptr, nullptr, nullptr,
        cPS, cDM, cDM, cDM, cPS, (long)cL * cDM, 0L, (long)cL * cPS, 1 << 30, 8);

    // 4. ts slices -> padded bf16 (2,B,L,64)
    tspad_kernel<<<1024, blk, 0, stream>>>(ssms, ts2_b);

    // 5. fused delta fwd+bwd: M=3072, N=L, K=64; B/bias switch at m=1536
    gemm_mfma<1><<<dim3(cL / 128, (2 * cDM) / 128, cB), blk, 0, stream>>>(
        dtw2_b, ts2_b, ts2_b + (long)cB * cL * 64,
        xbuf /*delta_f*/, deltab, dtb, dtbb,
        cL, 64, 64, 64, cL, 0L, (long)cL * 64, (long)cDM * cL, cDM, 1);

    // 6. chunked parallel scan: A (local summaries) -> B (compose) -> C (full)
    scanA_kernel<<<dim3(cDM / 16, cB, 2 * cCK), blk, 0, stream>>>(
        conv, xbuf /*delta_f*/, deltab, ssms, Alog, Alogb, sumAp, sumXf);
    scanB_kernel<<<dim3((int)(nSum / cCK / 16)), blk, 0, stream>>>(sumAp, sumXf, sumX0);
    scanC_kernel<<<dim3(cDM / 16, cB, 2 * cCK), blk, 0, stream>>>(
        conv, gate, xbuf /*delta_f*/, deltab, ssms,
        Alog, Alogb, Dv, Dbv, sumX0, yf_b, yb_b);

    // 7. combine: yf += yb (in place, bf16, 16B/thread)
    comb_kernel<<<(int)(S / 8 / 256), blk, 0, stream>>>(yf_b, yb_b, S / 8);

    // 8. out_proj: M=L, N=H, K=DM, split-K=2 (out zeroed above)
    gemm_mfma<2><<<dim3(cH / 128, cL / 128, cB * 2), blk, 0, stream>>>(
        yf_b, outw_b, nullptr, out, nullptr, nullptr, nullptr,
        cH, cDM, cDM, cDM, cH, (long)cL * cDM, 0L, (long)cL * cH, 1 << 30, 2);
}

// Round 8
// 187.597 us; speedup vs baseline: 1.8480x; 1.7228x over previous
//
#include <hip/hip_runtime.h>
#include <math.h>

// Problem constants
constexpr int cH  = 768;
constexpr int cDM = 1536;
constexpr int cN  = 16;
constexpr int cR  = 48;
constexpr int cB  = 2;
constexpr int cL  = 1024;
constexpr int cPS = 160;  // stacked ssm row: [fwd 80 | bwd 80]
constexpr int cCK = 8;    // scan chunks (chunk length = cL/cCK = 128)

typedef unsigned short u16;
typedef __attribute__((ext_vector_type(8))) short bf16x8;
typedef __attribute__((ext_vector_type(4))) float f32x4;

__device__ __forceinline__ u16 f2bf(float f) {
    unsigned u = __float_as_uint(f);
    u += 0x7FFF + ((u >> 16) & 1);          // RNE
    return (u16)(u >> 16);
}
__device__ __forceinline__ float bf2f(u16 h) {
    return __uint_as_float((unsigned)h << 16);
}

// 16-lane butterfly sum via DPP (VALU only, no LDS pipe)
__device__ __forceinline__ float row16_sum(float y) {
    int v;
    v = __builtin_amdgcn_update_dpp(0, __float_as_int(y), 0xB1, 0xF, 0xF, true);
    y += __int_as_float(v);
    v = __builtin_amdgcn_update_dpp(0, __float_as_int(y), 0x4E, 0xF, 0xF, true);
    y += __int_as_float(v);
    v = __builtin_amdgcn_update_dpp(0, __float_as_int(y), 0x141, 0xF, 0xF, true);
    y += __int_as_float(v);
    v = __builtin_amdgcn_update_dpp(0, __float_as_int(y), 0x140, 0xF, 0xF, true);
    y += __int_as_float(v);
    return y;
}

// ---------------------------------------------------------------------------
// prep: ALL weight/input bf16 converts + pads in ONE launch (was 7 kernels).
// Regions concatenated in output-element space; every region size % 8 == 0.
// ---------------------------------------------------------------------------
__global__ __launch_bounds__(256)
void prep_kernel(const float* __restrict__ hid, const float* __restrict__ inw,
                 const float* __restrict__ xpw, const float* __restrict__ xpbw,
                 const float* __restrict__ outw, const float* __restrict__ dtw,
                 const float* __restrict__ dtbw,
                 u16* __restrict__ hid_b, u16* __restrict__ inw_b,
                 u16* __restrict__ xpw2_b, u16* __restrict__ outw_b,
                 u16* __restrict__ dtw2_b)
{
    const long i8 = ((long)blockIdx.x * 256 + threadIdx.x) * 8;
    const long e0 = 1572864;            // hid    B*L*H
    const long e1 = e0 + 2359296;       // inw    2*DM*H
    const long e2 = e1 + 122880;        // xpw    80*DM
    const long e3 = e2 + 122880;        // xpbw
    const long e4 = e3 + 1179648;       // outw   H*DM
    const long e5 = e4 + 98304;         // dtw  pad 48->64 (DM rows)
    const long e6 = e5 + 98304;         // dtbw pad
    const float* in; u16* out; long off; int pad = 0;
    if      (i8 < e0) { in = hid;  out = hid_b;           off = i8; }
    else if (i8 < e1) { in = inw;  out = inw_b;           off = i8 - e0; }
    else if (i8 < e2) { in = xpw;  out = xpw2_b;          off = i8 - e1; }
    else if (i8 < e3) { in = xpbw; out = xpw2_b + 122880; off = i8 - e2; }
    else if (i8 < e4) { in = outw; out = outw_b;          off = i8 - e3; }
    else if (i8 < e5) { in = dtw;  out = dtw2_b;          off = i8 - e4; pad = 1; }
    else if (i8 < e6) { in = dtbw; out = dtw2_b + 98304;  off = i8 - e5; pad = 1; }
    else return;
    u16 o[8];
    if (!pad) {
        const float4 a = *(const float4*)&in[off];
        const float4 b = *(const float4*)&in[off + 4];
        o[0]=f2bf(a.x); o[1]=f2bf(a.y); o[2]=f2bf(a.z); o[3]=f2bf(a.w);
        o[4]=f2bf(b.x); o[5]=f2bf(b.y); o[6]=f2bf(b.z); o[7]=f2bf(b.w);
    } else {
        const long r = off >> 6; const int k0 = (int)(off & 63);
        #pragma unroll
        for (int k = 0; k < 8; ++k)
            o[k] = (k0 + k < cR) ? f2bf(in[r * cR + k0 + k]) : (u16)0;
    }
    *(uint4*)&out[off] = *(uint4*)o;
}

// ssms (B,L,160) ts-slices -> (2,B,L,64) bf16 zero-padded
__global__ __launch_bounds__(256)
void tspad_kernel(const float* __restrict__ ssms, u16* __restrict__ out) {
    int i = blockIdx.x * 256 + threadIdx.x;    // exactly 2*B*L*64 = 262144
    int dirsel = i >> 17;
    int rem = i & 131071;
    int bl = rem >> 6, k = rem & 63;
    out[i] = (k < cR) ? f2bf(ssms[(long)bl * cPS + dirsel * 80 + k]) : (u16)0;
}

__global__ __launch_bounds__(256)
void comb_kernel(u16* __restrict__ yf, const u16* __restrict__ yb, long n8) {
    long i = (long)blockIdx.x * 256 + threadIdx.x;
    if (i >= n8) return;
    uint4 av = ((uint4*)yf)[i];
    uint4 bv = ((const uint4*)yb)[i];
    unsigned* ap = (unsigned*)&av;
    unsigned* bp = (unsigned*)&bv;
    #pragma unroll
    for (int j = 0; j < 4; ++j) {
        const float lo = bf2f((u16)(ap[j] & 0xffff)) + bf2f((u16)(bp[j] & 0xffff));
        const float hi = bf2f((u16)(ap[j] >> 16))    + bf2f((u16)(bp[j] >> 16));
        ap[j] = (unsigned)f2bf(lo) | ((unsigned)f2bf(hi) << 16);
    }
    ((uint4*)yf)[i] = av;
}

// ---------------------------------------------------------------------------
// bf16 MFMA NT GEMM, 64x128 tile (A shared by 4 waves; wave w owns cols
// w*32..w*32+31). BK=32. Statically-named double buffers so the compiler can
// disambiguate ds_read(bufX) from in-flight global_load_lds(bufY).
// EPI: 0=store, 1=softplus(v+bias), 2=atomicAdd (split-K).
// ---------------------------------------------------------------------------
__device__ __forceinline__ void gld_lds16(const u16* g, u16* l) {
    __builtin_amdgcn_global_load_lds(
        (const __attribute__((address_space(1))) unsigned int*)g,
        (__attribute__((address_space(3))) unsigned int*)l, 16, 0, 0);
}

// 12 stage units of 1KB: 4 for A (64x32), 8 for B (128x32); 3 per wave.
#define GST(SA, SB, k0) do {                                                   \
    _Pragma("unroll")                                                          \
    for (int h = 0; h < 3; ++h) {                                              \
        const int q  = wid * 3 + h;                                            \
        const int rw = lane >> 2;                                              \
        if (q < 4) {                                                           \
            const int r  = q * 16 + rw;                                        \
            const int sw = (r & 3) ^ ((r >> 2) & 3);                           \
            const int kg = (k0) + (((lane & 3) ^ sw) << 3);                    \
            gld_lds16(Ab + (long)(m0 + r) * lda + kg, &SA[q * 512]);           \
        } else {                                                               \
            const int r  = (q - 4) * 16 + rw;                                  \
            const int sw = (r & 3) ^ ((r >> 2) & 3);                           \
            const int kg = (k0) + (((lane & 3) ^ sw) << 3);                    \
            int nr = n0 + r; if (nr > N2 - 1) nr = N2 - 1;                     \
            gld_lds16(Bb + (long)nr * ldb + kg, &SB[(q - 4) * 512]);           \
        }                                                                      \
    }                                                                          \
} while (0)

#define CMP(SA, SB) do {                                                       \
    bf16x8 af[4], bfr[2];                                                      \
    _Pragma("unroll")                                                          \
    for (int i = 0; i < 4; ++i) {                                              \
        const int ra  = i * 16 + lr;                                           \
        const int swa = (ra & 3) ^ ((ra >> 2) & 3);                            \
        af[i] = *(const bf16x8*)&SA[ra * 32 + ((lc ^ swa) << 3)];              \
    }                                                                          \
    _Pragma("unroll")                                                          \
    for (int j = 0; j < 2; ++j) {                                              \
        const int rb  = wn + j * 16 + lr;                                      \
        const int swb = (rb & 3) ^ ((rb >> 2) & 3);                            \
        bfr[j] = *(const bf16x8*)&SB[rb * 32 + ((lc ^ swb) << 3)];             \
    }                                                                          \
    _Pragma("unroll")                                                          \
    for (int i = 0; i < 4; ++i)                                                \
        _Pragma("unroll")                                                      \
        for (int j = 0; j < 2; ++j)                                            \
            acc[i][j] = __builtin_amdgcn_mfma_f32_16x16x32_bf16(af[i], bfr[j], acc[i][j], 0, 0, 0); \
} while (0)

template<int EPI>
__global__ __launch_bounds__(256, 4)
void gemm_mfma(const u16* __restrict__ A, const u16* __restrict__ B,
               const u16* __restrict__ B_hi,
               float* __restrict__ C0, float* __restrict__ C1,
               const float* __restrict__ bias, const float* __restrict__ bias_hi,
               int N2, int Kd, int lda, int ldb, int ldc,
               long sA, long sB, long sC, int splitRow, int kspl)
{
    __shared__ __align__(16) u16 shA0[2048];   // [64][32]
    __shared__ __align__(16) u16 shA1[2048];
    __shared__ __align__(16) u16 shB0[4096];   // [128][32]
    __shared__ __align__(16) u16 shB1[4096];
    const int tid  = threadIdx.x;
    const int wid  = tid >> 6, lane = tid & 63;
    const int lr   = lane & 15, lc = lane >> 4;
    const int z    = blockIdx.z;
    const int bz   = z / kspl, ks = z % kspl;
    const int kpc  = Kd / kspl;
    const int kbeg = ks * kpc;
    const int nt   = kpc / 32;
    const int n0 = blockIdx.x * 128, m0 = blockIdx.y * 64;
    const int wn = wid * 32;

    const u16* Bsel = (B_hi != nullptr && m0 >= splitRow) ? B_hi : B;
    const float* biasp = (bias_hi != nullptr && m0 >= splitRow) ? bias_hi : bias;
    const int mro = (bias_hi != nullptr && m0 >= splitRow) ? splitRow : 0;

    const u16* Ab = A + (long)bz * sA;
    const u16* Bb = Bsel + (long)bz * sB;

    f32x4 acc[4][2] = {};

    GST(shA0, shB0, kbeg);
    __syncthreads();
    int t = 0;
    for (;;) {
        if (t + 1 < nt) GST(shA1, shB1, kbeg + (t + 1) * 32);
        CMP(shA0, shB0);
        __syncthreads();
        if (++t >= nt) break;
        if (t + 1 < nt) GST(shA0, shB0, kbeg + (t + 1) * 32);
        CMP(shA1, shB1);
        __syncthreads();
        if (++t >= nt) break;
    }

    #pragma unroll
    for (int i = 0; i < 4; ++i) {
        #pragma unroll
        for (int e = 0; e < 4; ++e) {
            const int m = m0 + i * 16 + lc * 4 + e;        // C/D row
            float* crow;
            if (C1 != nullptr && m >= splitRow)
                crow = C1 + (long)bz * sC + (long)(m - splitRow) * ldc;
            else
                crow = C0 + (long)bz * sC + (long)m * ldc;
            const float bi = (EPI == 1) ? biasp[m - mro] : 0.f;
            #pragma unroll
            for (int j = 0; j < 2; ++j) {
                const int n = n0 + wn + j * 16 + lr;       // C/D col
                if (n < N2) {
                    float v = acc[i][j][e];
                    if (EPI == 1) {
                        const float t2 = v + bi;
                        v = fmaxf(t2, 0.f) + __logf(1.f + __expf(-fabsf(t2)));
                    }
                    if (EPI == 2) atomicAdd(crow + n, v);
                    else          crow[n] = v;
                }
            }
        }
    }
}

// ---------------------------------------------------------------------------
// Depthwise causal conv (K=4) + bias + SiLU, 32x32 LDS tiles.
// ---------------------------------------------------------------------------
__global__ __launch_bounds__(256)
void conv_silu_t(const float* __restrict__ x, const float* __restrict__ cw,
                 const float* __restrict__ cb,
                 float* __restrict__ conv, u16* __restrict__ convT)
{
    __shared__ float xs_[32][36];   // [d][l0-3 .. l0+31]
    __shared__ float cs[32][33];    // [l][d]
    const int l0 = blockIdx.x * 32, d0 = blockIdx.y * 32, b = blockIdx.z;
    const int lx = threadIdx.x & 31, dy = threadIdx.x >> 5;

    #pragma unroll
    for (int r = 0; r < 4; ++r) {
        const int dd = dy + r * 8;
        const float* xr = x + ((long)b * cDM + d0 + dd) * cL;
        const int li = l0 - 3 + lx;
        xs_[dd][lx] = (li >= 0) ? xr[li] : 0.f;
        if (lx < 3) xs_[dd][32 + lx] = xr[l0 + 29 + lx];
    }
    __syncthreads();
    #pragma unroll
    for (int r = 0; r < 4; ++r) {
        const int dd = dy + r * 8;
        const int d = d0 + dd;
        const float w0 = cw[d*4], w1 = cw[d*4+1], w2 = cw[d*4+2], w3 = cw[d*4+3];
        float v = cb[d];
        v = fmaf(w0, xs_[dd][lx],     v);
        v = fmaf(w1, xs_[dd][lx + 1], v);
        v = fmaf(w2, xs_[dd][lx + 2], v);
        v = fmaf(w3, xs_[dd][lx + 3], v);
        const float s = v / (1.f + __expf(-v));   // SiLU
        conv[((long)b * cDM + d) * cL + l0 + lx] = s;
        cs[lx][dd] = s;
    }
    __syncthreads();
    #pragma unroll
    for (int r = 0; r < 4; ++r) {
        const int ll = dy + r * 8;
        convT[((long)b * cL + l0 + ll) * cDM + d0 + lx] = f2bf(cs[ll][lx]);
    }
}

// ---------------------------------------------------------------------------
// Chunked parallel scan (8 chunks of 128 steps), 3 phases.
// ---------------------------------------------------------------------------
#define SC_LOAD(w) do {                                                       \
    const int ta_ = tb0 + (w) * 32;                                           \
    const int lb_ = dir ? (cL - 1 - (ta_ + t_bc)) : (ta_ + t_bc);             \
    rbc = *(const float4*)&sp[(long)lb_ * cPS + sofs + cc0];                  \
    const int tu_ = ta_ + 2 * n;                                              \
    if (!dir) {                                                               \
        ru2 = *(const float2*)&up[tu_];                                       \
        rd2 = *(const float2*)&dp[tu_];                                       \
    } else {                                                                  \
        const float2 a_ = *(const float2*)&up[cL - 2 - tu_];                  \
        const float2 b_ = *(const float2*)&dp[cL - 2 - tu_];                  \
        ru2 = make_float2(a_.y, a_.x);                                        \
        rd2 = make_float2(b_.y, b_.x);                                        \
    }                                                                         \
} while (0)

#define SC_WRITE(bufi) do {                                                   \
    bcS[bufi][cc0 + 0][t_bc] = rbc.x;                                         \
    bcS[bufi][cc0 + 1][t_bc] = rbc.y;                                         \
    bcS[bufi][cc0 + 2][t_bc] = rbc.z;                                         \
    bcS[bufi][cc0 + 3][t_bc] = rbc.w;                                         \
    *(float2*)&dS[bufi][g][2 * n]   = rd2;                                    \
    *(float2*)&duuS[bufi][g][2 * n] = make_float2(rd2.x * ru2.x, rd2.y * ru2.y); \
} while (0)

__global__ __launch_bounds__(256)
void scanA_kernel(const float* __restrict__ conv,
                  const float* __restrict__ delta_f,
                  const float* __restrict__ delta_b,
                  const float* __restrict__ ssms,
                  const float* __restrict__ Alog_f,
                  const float* __restrict__ Alog_b,
                  float* __restrict__ Ap_out, float* __restrict__ Xf_out)
{
    __shared__ float bcS[2][32][36];
    __shared__ float dS[2][16][36];
    __shared__ float duuS[2][16][36];

    const int tid = threadIdx.x;
    const int g = tid >> 4, n = tid & 15;
    const int d = blockIdx.x * 16 + g;
    const int b = blockIdx.y;
    const int z = blockIdx.z;
    const int dir = z >> 3, ck = z & 7;

    const float* delta = dir ? delta_b : delta_f;
    const float* Alog  = dir ? Alog_b  : Alog_f;
    const float a = -__expf(Alog[d * cN + n]);
    const int sofs = dir ? 128 : 48;

    const int t_bc = tid >> 3;
    const int cc0  = (tid & 7) << 2;
    const int tb0  = ck * (cL / cCK);

    const float* up = conv  + ((long)b * cDM + d) * cL;
    const float* dp = delta + ((long)b * cDM + d) * cL;
    const float* sp = ssms + (long)b * cL * cPS;

    float4 rbc; float2 ru2, rd2;
    SC_LOAD(0);
    SC_WRITE(0);
    __syncthreads();

    float xs = 0.f, Ap = 1.f;
    for (int w = 0; w < (cL / cCK) / 32; ++w) {
        const int cur = w & 1;
        if (w < (cL / cCK) / 32 - 1) SC_LOAD(w + 1);

        #pragma unroll
        for (int s = 0; s < 4; ++s) {
            const int t0 = s * 8;
            const float4 b0  = *(const float4*)&bcS[cur][n][t0];
            const float4 b1  = *(const float4*)&bcS[cur][n][t0 + 4];
            const float4 dd0 = *(const float4*)&dS[cur][g][t0];
            const float4 dd1 = *(const float4*)&dS[cur][g][t0 + 4];
            const float4 uu0 = *(const float4*)&duuS[cur][g][t0];
            const float4 uu1 = *(const float4*)&duuS[cur][g][t0 + 4];
            float dA[8], dBu[8];
            dA[0]=__expf(dd0.x*a); dA[1]=__expf(dd0.y*a); dA[2]=__expf(dd0.z*a); dA[3]=__expf(dd0.w*a);
            dA[4]=__expf(dd1.x*a); dA[5]=__expf(dd1.y*a); dA[6]=__expf(dd1.z*a); dA[7]=__expf(dd1.w*a);
            dBu[0]=uu0.x*b0.x; dBu[1]=uu0.y*b0.y; dBu[2]=uu0.z*b0.z; dBu[3]=uu0.w*b0.w;
            dBu[4]=uu1.x*b1.x; dBu[5]=uu1.y*b1.y; dBu[6]=uu1.z*b1.z; dBu[7]=uu1.w*b1.w;
            #pragma unroll
            for (int k = 0; k < 8; ++k) {
                xs = fmaf(dA[k], xs, dBu[k]);
                Ap *= dA[k];
            }
        }
        if (w < (cL / cCK) / 32 - 1) SC_WRITE(cur ^ 1);
        __syncthreads();
    }
    const long idx = (((long)(b * 2 + dir) * cDM + d) * cCK + ck) * 16 + n;
    Ap_out[idx] = Ap;
    Xf_out[idx] = xs;
}

__global__ __launch_bounds__(256)
void scanB_kernel(const float* __restrict__ Ap, const float* __restrict__ Xf,
                  float* __restrict__ X0)
{
    const int gid = blockIdx.x * 256 + threadIdx.x;  // exactly 2*B*DM*16 = 98304
    const int n = gid & 15;
    const long s = gid >> 4;                          // stream id
    float x0 = 0.f;
    #pragma unroll
    for (int c = 0; c < cCK; ++c) {
        const long idx = (s * cCK + c) * 16 + n;
        X0[idx] = x0;
        x0 = fmaf(Ap[idx], x0, Xf[idx]);
    }
}

__global__ __launch_bounds__(256)
void scanC_kernel(const float* __restrict__ conv,
                  const float* __restrict__ gate,
                  const float* __restrict__ delta_f,
                  const float* __restrict__ delta_b,
                  const float* __restrict__ ssms,
                  const float* __restrict__ Alog_f,
                  const float* __restrict__ Alog_b,
                  const float* __restrict__ D_f, const float* __restrict__ D_b,
                  const float* __restrict__ X0,
                  u16* __restrict__ yf, u16* __restrict__ yb)
{
    __shared__ float bcS[2][32][36];
    __shared__ float dS[2][16][36];
    __shared__ float duuS[2][16][36];

    const int tid = threadIdx.x;
    const int g = tid >> 4, n = tid & 15;
    const int d = blockIdx.x * 16 + g;
    const int b = blockIdx.y;
    const int z = blockIdx.z;
    const int dir = z >> 3, ck = z & 7;

    const float* delta = dir ? delta_b : delta_f;
    const float* Alog  = dir ? Alog_b  : Alog_f;
    const float  Dd    = dir ? D_b[d]  : D_f[d];
    u16*         yout  = dir ? yb      : yf;
    const float  a     = -__expf(Alog[d * cN + n]);
    const int    sofs  = dir ? 128 : 48;

    const int t_bc = tid >> 3;
    const int cc0  = (tid & 7) << 2;
    const int tb0  = ck * (cL / cCK);

    const float* up = conv  + ((long)b * cDM + d) * cL;
    const float* gp = gate  + ((long)b * cDM + d) * cL;
    const float* dp = delta + ((long)b * cDM + d) * cL;
    const float* sp = ssms + (long)b * cL * cPS;

    float xs = X0[(((long)(b * 2 + dir) * cDM + d) * cCK + ck) * 16 + n];

    float4 rbc; float2 ru2, rd2;
    SC_LOAD(0);
    SC_WRITE(0);
    __syncthreads();

    for (int w = 0; w < (cL / cCK) / 32; ++w) {
        const int cur = w & 1;
        if (w < (cL / cCK) / 32 - 1) SC_LOAD(w + 1);

        #pragma unroll
        for (int s = 0; s < 4; ++s) {
            const int t0 = s * 8;
            const float4 b0  = *(const float4*)&bcS[cur][n][t0];
            const float4 b1  = *(const float4*)&bcS[cur][n][t0 + 4];
            const float4 c0  = *(const float4*)&bcS[cur][16 + n][t0];
            const float4 c1  = *(const float4*)&bcS[cur][16 + n][t0 + 4];
            const float4 dd0 = *(const float4*)&dS[cur][g][t0];
            const float4 dd1 = *(const float4*)&dS[cur][g][t0 + 4];
            const float4 uu0 = *(const float4*)&duuS[cur][g][t0];
            const float4 uu1 = *(const float4*)&duuS[cur][g][t0 + 4];
            float dA[8], dBu[8], C8[8];
            dA[0]=__expf(dd0.x*a); dA[1]=__expf(dd0.y*a); dA[2]=__expf(dd0.z*a); dA[3]=__expf(dd0.w*a);
            dA[4]=__expf(dd1.x*a); dA[5]=__expf(dd1.y*a); dA[6]=__expf(dd1.z*a); dA[7]=__expf(dd1.w*a);
            dBu[0]=uu0.x*b0.x; dBu[1]=uu0.y*b0.y; dBu[2]=uu0.z*b0.z; dBu[3]=uu0.w*b0.w;
            dBu[4]=uu1.x*b1.x; dBu[5]=uu1.y*b1.y; dBu[6]=uu1.z*b1.z; dBu[7]=uu1.w*b1.w;
            C8[0]=c0.x; C8[1]=c0.y; C8[2]=c0.z; C8[3]=c0.w;
            C8[4]=c1.x; C8[5]=c1.y; C8[6]=c1.z; C8[7]=c1.w;

            float yo = 0.f;
            #pragma unroll
            for (int k = 0; k < 8; ++k) {
                xs = fmaf(dA[k], xs, dBu[k]);           // only serial dependence
                const float y = row16_sum(xs * C8[k]);  // DPP, VALU-only
                if (n == k) yo = y;
            }
            if (n < 8) {
                const int wt = tb0 + w * 32 + t0 + n;
                const int l  = dir ? (cL - 1 - wt) : wt;
                const float uu = up[l];
                const float gv = gp[l];
                const float val = (yo + uu * Dd) * (gv / (1.f + __expf(-gv)));
                yout[((long)b * cL + l) * cDM + d] = f2bf(val);
            }
        }
        if (w < (cL / cCK) / 32 - 1) SC_WRITE(cur ^ 1);
        __syncthreads();
    }
}

// ---------------------------------------------------------------------------
extern "C" void kernel_launch(void* const* d_in, const int* in_sizes, int n_in,
                              void* d_out, int out_size, void* d_ws, size_t ws_size,
                              hipStream_t stream)
{
    const float* hid   = (const float*)d_in[0];   // (B,L,H)
    const float* inw   = (const float*)d_in[1];   // (2DM,H)
    const float* convw = (const float*)d_in[2];   // (DM,K)
    const float* convb = (const float*)d_in[3];   // (DM)
    const float* xpw   = (const float*)d_in[4];   // (80,DM)
    const float* dtw   = (const float*)d_in[5];   // (DM,R)
    const float* dtb   = (const float*)d_in[6];   // (DM)
    const float* xpbw  = (const float*)d_in[7];
    const float* dtbw  = (const float*)d_in[8];
    const float* dtbb  = (const float*)d_in[9];
    const float* Alog  = (const float*)d_in[10];  // (DM,16)
    const float* Alogb = (const float*)d_in[11];
    const float* Dv    = (const float*)d_in[12];
    const float* Dbv   = (const float*)d_in[13];
    const float* outw  = (const float*)d_in[14];  // (H,DM)
    float* out = (float*)d_out;                   // (B,L,H)

    float* ws = (float*)d_ws;
    const long S = (long)cB * cDM * cL;           // 3,145,728
    float* xbuf   = ws;                // x, then delta_f
    float* gate   = ws + S;
    float* conv   = ws + 2 * S;        // u fp32 (b,d,l)
    float* deltab = ws + 3 * S;
    float* ssms   = ws + 4 * S;        // (B,L,160) fp32
    u16* up0      = (u16*)(ssms + (long)cB * cL * cPS);
    u16* convT_b  = up0;                              // S u16; later yf
    u16* ts2_b    = up0 + S;                          // 2*B*L*64 = 262,144
    u16* xpw2_b   = ts2_b + (long)2 * cB * cL * 64;   // 160*DM stacked
    u16* dtw2_b   = xpw2_b + (long)cPS * cDM;         // 2*DM*64 stacked
    u16* outw_b   = dtw2_b + (long)2 * cDM * 64;      // H*DM
    u16* pool2    = outw_b + (long)cH * cDM;          // 3,932,160 u16
    u16* inw_b    = pool2;                            // 2*DM*H (phase 1)
    u16* hid_b    = pool2 + (long)2 * cDM * cH;       // B*L*H  (phase 1)
    u16* yf_b     = convT_b;                          // phase 2 (after x_proj)
    u16* yb_b     = pool2;                            // phase 2 (after in_proj)
    const long nSum = (long)2 * cB * cDM * cCK * 16;  // 786,432 floats
    float* sumAp  = (float*)(pool2 + 3932160);
    float* sumXf  = sumAp + nSum;
    float* sumX0  = sumXf + nSum;

    const dim3 blk(256);

    // 0. all converts in one launch (out-space = 5,554,176 elems / 8 / 256)
    prep_kernel<<<dim3(2713), blk, 0, stream>>>(
        hid, inw, xpw, xpbw, outw, dtw, dtbw,
        hid_b, inw_b, xpw2_b, outw_b, dtw2_b);

    // split-K atomic targets must be zeroed
    hipMemsetAsync(ssms, 0, (long)cB * cL * cPS * sizeof(float), stream);
    hipMemsetAsync(out, 0, (long)out_size * sizeof(float), stream);

    // 1. in_proj (M=3072, N=L, K=H), split x | gate. grid 768 blocks.
    gemm_mfma<0><<<dim3(cL / 128, (2 * cDM) / 64, cB), blk, 0, stream>>>(
        inw_b, hid_b, nullptr, xbuf, gate, nullptr, nullptr,
        cL, cH, cH, cH, cL, 0L, (long)cL * cH, (long)cDM * cL, cDM, 1);

    // 2. causal conv + SiLU (tiled; both outputs coalesced)
    conv_silu_t<<<dim3(cL / 32, cDM / 32, cB), blk, 0, stream>>>(
        xbuf, convw, convb, conv, convT_b);

    // 3. fused x_proj fwd+bwd: M=L, N=160, K=DM, split-K=8. 512 blocks.
    gemm_mfma<2><<<dim3(2, cL / 64, cB * 8), blk, 0, stream>>>(
        convT_b, xpw2_b, nullptr, ssms, nullptr, nullptr, nullptr,
        cPS, cDM, cDM, cDM, cPS, (long)cL * cDM, 0L, (long)cL * cPS, 1 << 30, 8);

    // 4. ts slices -> padded bf16 (2,B,L,64)
    tspad_kernel<<<1024, blk, 0, stream>>>(ssms, ts2_b);

    // 5. fused delta fwd+bwd: M=3072, N=L, K=64. 768 blocks.
    gemm_mfma<1><<<dim3(cL / 128, (2 * cDM) / 64, cB), blk, 0, stream>>>(
        dtw2_b, ts2_b, ts2_b + (long)cB * cL * 64,
        xbuf /*delta_f*/, deltab, dtb, dtbb,
        cL, 64, 64, 64, cL, 0L, (long)cL * 64, (long)cDM * cL, cDM, 1);

    // 6. chunked parallel scan: A -> B -> C
    scanA_kernel<<<dim3(cDM / 16, cB, 2 * cCK), blk, 0, stream>>>(
        conv, xbuf /*delta_f*/, deltab, ssms, Alog, Alogb, sumAp, sumXf);
    scanB_kernel<<<dim3(384), blk, 0, stream>>>(sumAp, sumXf, sumX0);
    scanC_kernel<<<dim3(cDM / 16, cB, 2 * cCK), blk, 0, stream>>>(
        conv, gate, xbuf /*delta_f*/, deltab, ssms,
        Alog, Alogb, Dv, Dbv, sumX0, yf_b, yb_b);

    // 7. combine: yf += yb (in place, bf16, 16B/thread)
    comb_kernel<<<(int)(S / 8 / 256), blk, 0, stream>>>(yf_b, yb_b, S / 8);

    // 8. out_proj: M=L, N=H, K=DM, split-K=2. 384 blocks.
    gemm_mfma<2><<<dim3(cH / 128, cL / 64, cB * 2), blk, 0, stream>>>(
        yf_b, outw_b, nullptr, out, nullptr, nullptr, nullptr,
        cH, cDM, cDM, cDM, cH, (long)cL * cDM, 0L, (long)cL * cH, 1 << 30, 2);
}